// Round 5
// baseline (273.120 us; speedup 1.0000x reference)
//
#include <hip/hip_runtime.h>
#include <hip/hip_fp16.h>

#define N_NODES 50000
#define MPAD    50048            // 782 * 64
#define N_EDGES 500000
#define F_IN    112
#define K1X     112              // X16 row stride (halves) - unpadded
#define K1P     128              // aX / w1t row stride (halves) - padded for MFMA
#define F1      336
#define K2P     352              // F1 padded to 32-multiple
#define F2      168
#define NGRAPH  256
#define SCAN_CHUNK 1024
#define SCAN_BLOCKS ((N_NODES + SCAN_CHUNK - 1) / SCAN_CHUNK)   // 49

typedef __attribute__((ext_vector_type(8))) _Float16 f16x8;
typedef __attribute__((ext_vector_type(4))) float f32x4;
typedef unsigned short ushort_t;

__device__ __forceinline__ ushort_t f16_bits(float x) {
    __half h = __float2half_rn(x);
    return *(ushort_t*)&h;
}

// ---- batched gather primitives: force N loads in flight (compiler won't; VGPR=40 evidence R2/R3) ----
__device__ __forceinline__ void gload_b64(uint2& d, const ushort_t* a) {
    asm volatile("global_load_dwordx2 %0, %1, off" : "=v"(d) : "v"(a));
}
__device__ __forceinline__ void gload_e(int2& d, const int2* a) {
    asm volatile("global_load_dwordx2 %0, %1, off" : "=v"(d) : "v"(a));
}
__device__ __forceinline__ void gload_b128(uint4& d, const ushort_t* a) {
    asm volatile("global_load_dwordx4 %0, %1, off" : "=v"(d) : "v"(a));
}
__device__ __forceinline__ void vmwait0() {
    asm volatile("s_waitcnt vmcnt(0)" ::: "memory");
    __builtin_amdgcn_sched_barrier(0);   // rule 18: block hoist of register-only consumers
}
__device__ __forceinline__ void vmwait8() {
    asm volatile("s_waitcnt vmcnt(8)" ::: "memory");
    __builtin_amdgcn_sched_barrier(0);
}

// ---------------- small utility kernels ----------------
__global__ void k_zero_int(int* p, int n) {
    int i = blockIdx.x * blockDim.x + threadIdx.x;
    if (i < n) p[i] = 0;
}

// ---------------- fused prep: cvtX(dense 112) | count_deg | cvtW1 | cvtW2 ----------------
#define CVX_ELEMS  (N_NODES * 28)                           // uint2 elems (4 halves each)
#define CVX_BLOCKS ((CVX_ELEMS + 255) / 256)                // 5469
#define CNT_BLOCKS  ((N_EDGES / 2 + 255) / 256)             // 977
#define CVW1_BLOCKS ((384 * K1P + 255) / 256)               // 192
#define CVW2_BLOCKS ((192 * K2P + 255) / 256)               // 264
#define PREP_BLOCKS (CVX_BLOCKS + CNT_BLOCKS + CVW1_BLOCKS + CVW2_BLOCKS)

__global__ __launch_bounds__(256) void k_prep(const float* __restrict__ x,
                                              const int* __restrict__ dst,
                                              const float* __restrict__ W1,
                                              const float* __restrict__ W2,
                                              ushort_t* __restrict__ x16,   // [N][112] unpadded
                                              int* __restrict__ dcount,
                                              ushort_t* __restrict__ w1t,   // [384][128]
                                              ushort_t* __restrict__ w2t) { // [192][352]
    int bid = blockIdx.x;
    int t = threadIdx.x;
    if (bid < CVX_BLOCKS) {                       // X fp32 -> fp16, dense (rows are 112 = 28*4)
        int i = bid * 256 + t;
        if (i < CVX_ELEMS) {
            float4 f = ((const float4*)x)[i];
            __half2 h0 = __floats2half2_rn(f.x, f.y);
            __half2 h1 = __floats2half2_rn(f.z, f.w);
            uint2 u; u.x = *(unsigned*)&h0; u.y = *(unsigned*)&h1;
            ((uint2*)x16)[i] = u;
        }
        return;
    }
    bid -= CVX_BLOCKS;
    if (bid < CNT_BLOCKS) {                       // degree count, 2 edges/thread
        int i = bid * 256 + t;
        if (i < N_EDGES / 2) {
            int2 d = ((const int2*)dst)[i];
            atomicAdd(&dcount[d.x], 1);
            atomicAdd(&dcount[d.y], 1);
        }
        return;
    }
    bid -= CNT_BLOCKS;
    if (bid < CVW1_BLOCKS) {                      // W1[K,N] -> w1t[n][k]
        int idx = bid * 256 + t;
        if (idx < 384 * K1P) {
            int n = idx / K1P, k = idx % K1P;
            float v = (n < F1 && k < F_IN) ? W1[k * F1 + n] : 0.0f;
            w1t[idx] = f16_bits(v);
        }
        return;
    }
    bid -= CVW1_BLOCKS;
    {                                             // W2[K,N] -> w2t[n][k]
        int idx = bid * 256 + t;
        if (idx < 192 * K2P) {
            int n = idx / K2P, k = idx % K2P;
            float v = (n < F2 && k < F1) ? W2[k * F2 + n] : 0.0f;
            w2t[idx] = f16_bits(v);
        }
    }
}

// ---------------- scan pass 1 (dinv fused) ----------------
__global__ __launch_bounds__(SCAN_CHUNK) void k_scan1(const int* __restrict__ dcount,
                                                      int* __restrict__ off,
                                                      int* __restrict__ partials,
                                                      float* __restrict__ dinv, int n) {
    __shared__ int s[SCAN_CHUNK];
    int t = threadIdx.x;
    int i = blockIdx.x * SCAN_CHUNK + t;
    int val = (i < n) ? dcount[i] : 0;
    s[t] = val;
    __syncthreads();
    for (int d = 1; d < SCAN_CHUNK; d <<= 1) {
        int x = (t >= d) ? s[t - d] : 0;
        __syncthreads();
        s[t] += x;
        __syncthreads();
    }
    if (i < n) {
        off[i] = s[t] - val;
        dinv[i] = rsqrtf((float)val + 1.0f);      // +1 self-loop
    }
    if (t == SCAN_CHUNK - 1) partials[blockIdx.x] = s[t];
}
// scan pass 2+3 merged
__global__ __launch_bounds__(SCAN_CHUNK) void k_scan3(int* __restrict__ off,
                                                      const int* __restrict__ partials, int n) {
    __shared__ int tmp[SCAN_BLOCKS];
    __shared__ int pref[SCAN_BLOCKS];
    int t = threadIdx.x;
    if (t < SCAN_BLOCKS) tmp[t] = partials[t];
    __syncthreads();
    if (t == 0) {
        int run = 0;
        for (int j = 0; j < SCAN_BLOCKS; ++j) { pref[j] = run; run += tmp[j]; }
    }
    __syncthreads();
    int i = blockIdx.x * SCAN_CHUNK + t;
    if (i < n) off[i] += pref[blockIdx.x];
    if (i == n) off[i] = N_EDGES;
}

// ---------------- scatter edges into dst-sorted CSR, 2 edges/thread ----------------
__global__ void k_scatter(const int* __restrict__ src, const int* __restrict__ dst,
                          const int* __restrict__ off, int* __restrict__ cur,
                          const float* __restrict__ dinv,
                          int2* __restrict__ csr, int e2) {
    int i = blockIdx.x * blockDim.x + threadIdx.x;
    if (i >= e2) return;
    int2 s2 = ((const int2*)src)[i];
    int2 d2 = ((const int2*)dst)[i];
    {
        int pos = atomicAdd(&cur[d2.x], 1);
        int2 rec; rec.x = s2.x; rec.y = __float_as_int(dinv[s2.x] * dinv[d2.x]);
        csr[off[d2.x] + pos] = rec;
    }
    {
        int pos = atomicAdd(&cur[d2.y], 1);
        int2 rec; rec.x = s2.y; rec.y = __float_as_int(dinv[s2.y] * dinv[d2.y]);
        csr[off[d2.y] + pos] = rec;
    }
}

// ---------------- agg layer 1: 2 nodes/wave, depth-16 pipelined gathers ----------------
__global__ __launch_bounds__(256) void k_agg1(const ushort_t* __restrict__ X16,  // [N][112]
                                              const int* __restrict__ off,
                                              const int2* __restrict__ csr,
                                              const float* __restrict__ dinv,
                                              ushort_t* __restrict__ aX) {       // [MPAD][128]
    int w = (blockIdx.x * 256 + threadIdx.x) >> 6;
    int lane = threadIdx.x & 63;
    if (w >= N_NODES / 2) return;
    const int g = lane >> 5, sl = lane & 31;
    const int slc = min(sl, 27);                  // clamp: pad lanes load row's last chunk, discard
    const int v = 2 * w + g;
    const bool act = sl < 28;                     // 28 lanes x 4 halves = 112
    int o0A = off[2 * w], oM = off[2 * w + 1], o1B = off[2 * w + 2];
    int o0 = g ? oM : o0A;
    int n  = g ? (o1B - oM) : (oM - o0A);
    int nmax = max(oM - o0A, o1B - oM);
    float di = dinv[v];
    float s2 = di * di;
    float4 acc;
    {
        uint2 us = *(const uint2*)(X16 + (long)v * K1X + slc * 4);
        float2 sf0 = __half22float2(*(__half2*)&us.x);
        float2 sf1 = __half22float2(*(__half2*)&us.y);
        acc.x = sf0.x * s2; acc.y = sf0.y * s2; acc.z = sf1.x * s2; acc.w = sf1.y * s2;
    }
    int nm1 = max(n - 1, 0);
    for (int b = 0; b < nmax; b += 16) {
        int2 e[16];
        #pragma unroll
        for (int j = 0; j < 16; ++j) {
            int cidx = min(o0 + min(b + j, nm1), N_EDGES - 1);
            gload_e(e[j], csr + cidx);            // uniform per half-wave -> broadcast
        }
        vmwait0();
        uint2 u[16];
        #pragma unroll
        for (int j = 0; j < 16; ++j)
            gload_b64(u[j], X16 + (long)e[j].x * K1X + slc * 4);
        vmwait8();                                // first 8 landed; last 8 still in flight
        #pragma unroll
        for (int j = 0; j < 8; ++j) {
            float c = ((b + j) < n) ? __int_as_float(e[j].y) : 0.0f;
            float2 f0 = __half22float2(*(__half2*)&u[j].x);
            float2 f1 = __half22float2(*(__half2*)&u[j].y);
            acc.x += c * f0.x; acc.y += c * f0.y; acc.z += c * f1.x; acc.w += c * f1.y;
        }
        vmwait0();
        #pragma unroll
        for (int j = 8; j < 16; ++j) {
            float c = ((b + j) < n) ? __int_as_float(e[j].y) : 0.0f;
            float2 f0 = __half22float2(*(__half2*)&u[j].x);
            float2 f1 = __half22float2(*(__half2*)&u[j].y);
            acc.x += c * f0.x; acc.y += c * f0.y; acc.z += c * f1.x; acc.w += c * f1.y;
        }
    }
    __half2 h0 = __floats2half2_rn(acc.x, acc.y);
    __half2 h1 = __floats2half2_rn(acc.z, acc.w);
    uint2 o; o.x = *(unsigned*)&h0; o.y = *(unsigned*)&h1;
    if (!act) { o.x = 0; o.y = 0; }               // pad lanes accumulated garbage -> zero
    *(uint2*)(aX + (long)v * K1P + sl * 4) = o;
}

// ---------------- fused GEMM1+GEMM2: T2 = (relu(aX@W1t^T + b1)) @ W2t^T ----------------
__global__ __launch_bounds__(256) void k_gemm_fused(
        const ushort_t* __restrict__ aX,    // [MPAD][128]
        const ushort_t* __restrict__ w1t,   // [384][128] rows 0..351 used
        const float* __restrict__ b1,       // [336]
        const ushort_t* __restrict__ w2t,   // [192][352]
        ushort_t* __restrict__ T2) {        // [MPAD][168]
    __shared__ ushort_t As[64][40];
    __shared__ ushort_t Bs[352][40];
    __shared__ ushort_t H1s[64][360];
    const int tid = threadIdx.x;
    const int row0 = blockIdx.x * 64;
    const int w = tid >> 6, l = tid & 63;
    const int wm = w >> 1, wn = w & 1;
    const int lm = l & 15, lq = l >> 4;

    // ---- phase 1 ----
    f32x4 acc1[2][11];
    #pragma unroll
    for (int i = 0; i < 2; ++i)
        #pragma unroll
        for (int j = 0; j < 11; ++j) acc1[i][j] = (f32x4){0.f, 0.f, 0.f, 0.f};

    for (int k0 = 0; k0 < K1P; k0 += 32) {
        {   // stage As
            int r = tid >> 2, s = (tid & 3) * 8;
            *(int4*)&As[r][s] = *(const int4*)&aX[(long)(row0 + r) * K1P + k0 + s];
        }
        #pragma unroll
        for (int it = 0; it < 6; ++it) {   // stage Bs: 352 rows x 4 segs = 1408
            int f = tid + it * 256;
            if (f < 1408) {
                int r = f >> 2, s = (f & 3) * 8;
                *(int4*)&Bs[r][s] = *(const int4*)&w1t[(long)r * K1P + k0 + s];
            }
        }
        __syncthreads();
        f16x8 af0 = *(const f16x8*)&As[wm * 32 + lm][lq * 8];
        f16x8 af1 = *(const f16x8*)&As[wm * 32 + 16 + lm][lq * 8];
        #pragma unroll
        for (int ns = 0; ns < 11; ++ns) {
            f16x8 bf = *(const f16x8*)&Bs[wn * 176 + ns * 16 + lm][lq * 8];
            acc1[0][ns] = __builtin_amdgcn_mfma_f32_16x16x32_f16(af0, bf, acc1[0][ns], 0, 0, 0);
            acc1[1][ns] = __builtin_amdgcn_mfma_f32_16x16x32_f16(af1, bf, acc1[1][ns], 0, 0, 0);
        }
        __syncthreads();
    }
    // write H1 tile to LDS with bias+relu (C/D layout: col=lm, row=lq*4+i)
    #pragma unroll
    for (int ms = 0; ms < 2; ++ms)
        #pragma unroll
        for (int ns = 0; ns < 11; ++ns) {
            int col = wn * 176 + ns * 16 + lm;
            float bb = (col < F1) ? b1[col] : 0.0f;
            #pragma unroll
            for (int i = 0; i < 4; ++i) {
                int r = wm * 32 + ms * 16 + lq * 4 + i;
                H1s[r][col] = f16_bits(fmaxf(acc1[ms][ns][i] + bb, 0.0f));
            }
        }
    __syncthreads();

    // ---- phase 2 ----
    f32x4 acc2[2][6];
    #pragma unroll
    for (int i = 0; i < 2; ++i)
        #pragma unroll
        for (int j = 0; j < 6; ++j) acc2[i][j] = (f32x4){0.f, 0.f, 0.f, 0.f};

    for (int k0 = 0; k0 < K2P; k0 += 32) {
        #pragma unroll
        for (int it = 0; it < 3; ++it) {   // stage Bs2: 192 rows x 4 segs = 768
            int f = tid + it * 256;
            int r = f >> 2, s = (f & 3) * 8;
            *(int4*)&Bs[r][s] = *(const int4*)&w2t[(long)r * K2P + k0 + s];
        }
        __syncthreads();
        f16x8 af0 = *(const f16x8*)&H1s[wm * 32 + lm][k0 + lq * 8];
        f16x8 af1 = *(const f16x8*)&H1s[wm * 32 + 16 + lm][k0 + lq * 8];
        #pragma unroll
        for (int ns = 0; ns < 6; ++ns) {
            f16x8 bf = *(const f16x8*)&Bs[wn * 96 + ns * 16 + lm][lq * 8];
            acc2[0][ns] = __builtin_amdgcn_mfma_f32_16x16x32_f16(af0, bf, acc2[0][ns], 0, 0, 0);
            acc2[1][ns] = __builtin_amdgcn_mfma_f32_16x16x32_f16(af1, bf, acc2[1][ns], 0, 0, 0);
        }
        __syncthreads();
    }
    #pragma unroll
    for (int ms = 0; ms < 2; ++ms)
        #pragma unroll
        for (int ns = 0; ns < 6; ++ns) {
            int col = wn * 96 + ns * 16 + lm;
            if (col < F2) {
                #pragma unroll
                for (int i = 0; i < 4; ++i) {
                    int r = row0 + wm * 32 + ms * 16 + lq * 4 + i;
                    T2[(long)r * F2 + col] = f16_bits(acc2[ms][ns][i]);
                }
            }
        }
}

// ---------------- agg layer 2 + fused global-max-pool (depth-16 pipelined gathers) ----------------
// 2 nodes/wave, bias+relu in f32, per-block segment max -> atomicMax(int) on gmax.
// Valid because post-relu values are >= 0 (int-bit compare == float compare) and gmax init = 0.
__global__ __launch_bounds__(256) void k_agg2(const ushort_t* __restrict__ T16,   // [MPAD][168]
                                              const int* __restrict__ off,
                                              const int2* __restrict__ csr,
                                              const float* __restrict__ dinv,
                                              const float* __restrict__ b2,
                                              const int* __restrict__ batch,
                                              float* __restrict__ gmax) {         // [256][168]
    __shared__ __align__(16) float smax[8][168];
    __shared__ int sb[8];
    int tid = threadIdx.x;
    // grid is exactly N_NODES/8 blocks -> every thread has a valid node (no early return: barrier below)
    int w = (blockIdx.x * 256 + tid) >> 6;
    int lane = tid & 63;
    const int g = lane >> 5, sl = lane & 31;
    const int slc = min(sl, 20);                  // clamp: pad lanes load row tail, discard
    const int nib = tid >> 5;                     // node-in-block 0..7
    const int v = 2 * w + g;                      // == blockIdx.x*8 + nib
    const bool act = sl < 21;                     // 21 lanes x 8 halves = 168
    int o0A = off[2 * w], oM = off[2 * w + 1], o1B = off[2 * w + 2];
    int o0 = g ? oM : o0A;
    int n  = g ? (o1B - oM) : (oM - o0A);
    int nmax = max(oM - o0A, o1B - oM);
    float di = dinv[v];
    float4 a0, a1;
    {
        uint4 u = *(const uint4*)(T16 + (long)v * F2 + slc * 8);
        float2 f0 = __half22float2(*(__half2*)&u.x);
        float2 f1 = __half22float2(*(__half2*)&u.y);
        float2 f2 = __half22float2(*(__half2*)&u.z);
        float2 f3 = __half22float2(*(__half2*)&u.w);
        float s2 = di * di;
        a0.x = f0.x * s2; a0.y = f0.y * s2; a0.z = f1.x * s2; a0.w = f1.y * s2;
        a1.x = f2.x * s2; a1.y = f2.y * s2; a1.z = f3.x * s2; a1.w = f3.y * s2;
    }
    int nm1 = max(n - 1, 0);
    for (int b = 0; b < nmax; b += 16) {
        int2 e[16];
        #pragma unroll
        for (int j = 0; j < 16; ++j) {
            int cidx = min(o0 + min(b + j, nm1), N_EDGES - 1);
            gload_e(e[j], csr + cidx);
        }
        vmwait0();
        uint4 u[16];
        #pragma unroll
        for (int j = 0; j < 16; ++j)
            gload_b128(u[j], T16 + (long)e[j].x * F2 + slc * 8);
        vmwait8();                                // first 8 landed; last 8 still in flight
        #pragma unroll
        for (int j = 0; j < 8; ++j) {
            float c = ((b + j) < n) ? __int_as_float(e[j].y) : 0.0f;
            float2 f0 = __half22float2(*(__half2*)&u[j].x);
            float2 f1 = __half22float2(*(__half2*)&u[j].y);
            float2 f2 = __half22float2(*(__half2*)&u[j].z);
            float2 f3 = __half22float2(*(__half2*)&u[j].w);
            a0.x += c * f0.x; a0.y += c * f0.y; a0.z += c * f1.x; a0.w += c * f1.y;
            a1.x += c * f2.x; a1.y += c * f2.y; a1.z += c * f3.x; a1.w += c * f3.y;
        }
        vmwait0();
        #pragma unroll
        for (int j = 8; j < 16; ++j) {
            float c = ((b + j) < n) ? __int_as_float(e[j].y) : 0.0f;
            float2 f0 = __half22float2(*(__half2*)&u[j].x);
            float2 f1 = __half22float2(*(__half2*)&u[j].y);
            float2 f2 = __half22float2(*(__half2*)&u[j].z);
            float2 f3 = __half22float2(*(__half2*)&u[j].w);
            a0.x += c * f0.x; a0.y += c * f0.y; a0.z += c * f1.x; a0.w += c * f1.y;
            a1.x += c * f2.x; a1.y += c * f2.y; a1.z += c * f3.x; a1.w += c * f3.y;
        }
    }
    if (act) {
        float4 bb0 = ((const float4*)b2)[sl * 2];
        float4 bb1 = ((const float4*)b2)[sl * 2 + 1];
        a0.x = fmaxf(a0.x + bb0.x, 0.0f); a0.y = fmaxf(a0.y + bb0.y, 0.0f);
        a0.z = fmaxf(a0.z + bb0.z, 0.0f); a0.w = fmaxf(a0.w + bb0.w, 0.0f);
        a1.x = fmaxf(a1.x + bb1.x, 0.0f); a1.y = fmaxf(a1.y + bb1.y, 0.0f);
        a1.z = fmaxf(a1.z + bb1.z, 0.0f); a1.w = fmaxf(a1.w + bb1.w, 0.0f);
        ((float4*)&smax[nib][0])[sl * 2]     = a0;
        ((float4*)&smax[nib][0])[sl * 2 + 1] = a1;
    }
    if ((tid & 31) == 0) sb[nib] = batch[v];
    __syncthreads();
    if (tid < F2) {
        int f = tid;
        int bp = sb[0];
        float m = smax[0][f];
        #pragma unroll
        for (int r = 1; r < 8; ++r) {
            int bc = sb[r];
            float vv = smax[r][f];
            if (bc == bp) { m = fmaxf(m, vv); }
            else {
                atomicMax((int*)&gmax[bp * F2 + f], __float_as_int(m));
                m = vv; bp = bc;
            }
        }
        atomicMax((int*)&gmax[bp * F2 + f], __float_as_int(m));
    }
}

// ---------------- MLP head on pooled [256][168] ----------------
__global__ __launch_bounds__(128) void k_head(const float* __restrict__ gmax,
        const float* __restrict__ Wg, const float* __restrict__ bg,
        const float* __restrict__ Wf, const float* __restrict__ bf,
        const float* __restrict__ Wo, const float* __restrict__ bo,
        float* __restrict__ out) {
    __shared__ float s1[84];
    __shared__ float s2[42];
    int gi = blockIdx.x;
    const float* s0 = gmax + (long)gi * F2;
    int t = threadIdx.x;
    if (t < 84) {
        float acc = bg[t];
        #pragma unroll 4
        for (int k = 0; k < F2; ++k) acc += s0[k] * Wg[k * 84 + t];
        s1[t] = fmaxf(acc, 0.0f);
    }
    __syncthreads();
    if (t < 42) {
        float acc = bf[t];
        #pragma unroll 4
        for (int k = 0; k < 84; ++k) acc += s1[k] * Wf[k * 42 + t];
        s2[t] = fmaxf(acc, 0.0f);
    }
    __syncthreads();
    if (t == 0) {
        float acc = bo[0];
        for (int k = 0; k < 42; ++k) acc += s2[k] * Wo[k];
        out[gi] = acc;
    }
}

extern "C" void kernel_launch(void* const* d_in, const int* in_sizes, int n_in,
                              void* d_out, int out_size, void* d_ws, size_t ws_size,
                              hipStream_t stream) {
    const float* x   = (const float*)d_in[0];
    const int*   ei  = (const int*)d_in[1];
    const int*   bat = (const int*)d_in[2];
    const float* W1  = (const float*)d_in[3];
    const float* b1  = (const float*)d_in[4];
    const float* W2  = (const float*)d_in[5];
    const float* b2  = (const float*)d_in[6];
    const float* Wg  = (const float*)d_in[7];
    const float* bg  = (const float*)d_in[8];
    const float* Wf  = (const float*)d_in[9];
    const float* bf  = (const float*)d_in[10];
    const float* Wo  = (const float*)d_in[11];
    const float* bo  = (const float*)d_in[12];
    float* out = (float*)d_out;

    // ---- workspace carve-up (16B-aligned chunks; dcount+cur+gmax adjacent for one zero-fill) ----
    char* p = (char*)d_ws;
    float* dinv     = (float*)p; p += 50048 * 4;
    int*   dcount   = (int*)p;   p += 50048 * 4;
    int*   cur      = (int*)p;   p += 50048 * 4;
    float* gmax     = (float*)p; p += NGRAPH * F2 * 4;              // 43008 floats
    int*   off      = (int*)p;   p += 50064 * 4;
    int*   partials = (int*)p;   p += 64 * 4;
    int2*  csr      = (int2*)p;  p += (long)N_EDGES * 8;
    ushort_t* x16   = (ushort_t*)p; p += (long)N_NODES * K1X * 2;   // unpadded 112
    ushort_t* aX    = (ushort_t*)p; p += (long)MPAD * K1P * 2;      // padded 128
    ushort_t* w1t   = (ushort_t*)p; p += (long)384 * K1P * 2;
    ushort_t* w2t   = (ushort_t*)p; p += (long)192 * K2P * 2;
    ushort_t* t16   = (ushort_t*)p; p += (long)MPAD * F2 * 2;       // unpadded 168

    const int* src = ei;
    const int* dst = ei + N_EDGES;
    const int B = 256;
    const int ZERO_WORDS = 50048 * 2 + NGRAPH * F2;                 // dcount+cur+gmax

    // ---- preproc ----
    k_zero_int<<<(ZERO_WORDS + B - 1) / B, B, 0, stream>>>(dcount, ZERO_WORDS);
    k_prep<<<PREP_BLOCKS, B, 0, stream>>>(x, dst, W1, W2, x16, dcount, w1t, w2t);
    k_scan1<<<SCAN_BLOCKS, SCAN_CHUNK, 0, stream>>>(dcount, off, partials, dinv, N_NODES);
    k_scan3<<<SCAN_BLOCKS, SCAN_CHUNK, 0, stream>>>(off, partials, N_NODES);
    k_scatter<<<(N_EDGES / 2 + B - 1) / B, B, 0, stream>>>(src, dst, off, cur, dinv, csr, N_EDGES / 2);

    // ---- layer 1 agg + fused GEMM1/GEMM2 ----
    k_agg1<<<(N_NODES / 2 * 64) / 256, 256, 0, stream>>>(x16, off, csr, dinv, aX);
    k_gemm_fused<<<MPAD / 64, 256, 0, stream>>>(aX, w1t, b1, w2t, t16);

    // ---- layer 2 agg + fused max-pool ----
    k_agg2<<<(N_NODES / 2 * 64) / 256, 256, 0, stream>>>(t16, off, csr, dinv, b2, bat, gmax);

    // ---- MLP head ----
    k_head<<<NGRAPH, 128, 0, stream>>>(gmax, Wg, bg, Wf, bf, Wo, bo, out);
}

// Round 6
// 256.193 us; speedup vs baseline: 1.0661x; 1.0661x over previous
//
#include <hip/hip_runtime.h>
#include <hip/hip_fp16.h>

#define N_NODES 50000
#define MPAD    50048            // 782 * 64
#define N_EDGES 500000
#define F_IN    112
#define K1X     112              // X16 row stride (halves) - unpadded
#define K1P     128              // aX / w1t row stride (halves) - padded for MFMA
#define F1      336
#define K2P     352              // F1 padded to 32-multiple
#define F2      168
#define NGRAPH  256
#define SCAN_CHUNK 1024
#define SCAN_BLOCKS ((N_NODES + SCAN_CHUNK - 1) / SCAN_CHUNK)   // 49

typedef __attribute__((ext_vector_type(8))) _Float16 f16x8;
typedef __attribute__((ext_vector_type(4))) float f32x4;
typedef unsigned short ushort_t;

__device__ __forceinline__ ushort_t f16_bits(float x) {
    __half h = __float2half_rn(x);
    return *(ushort_t*)&h;
}

// ---- batched gather primitives: force N loads in flight (compiler won't; VGPR=40 evidence R2/R3) ----
__device__ __forceinline__ void gload_b64(uint2& d, const ushort_t* a) {
    asm volatile("global_load_dwordx2 %0, %1, off" : "=v"(d) : "v"(a));
}
__device__ __forceinline__ void gload_b128(uint4& d, const ushort_t* a) {
    asm volatile("global_load_dwordx4 %0, %1, off" : "=v"(d) : "v"(a));
}
__device__ __forceinline__ void vmwait0() {
    asm volatile("s_waitcnt vmcnt(0)" ::: "memory");
    __builtin_amdgcn_sched_barrier(0);   // rule 18: block hoist of register-only consumers
}

// ---------------- small utility kernels ----------------
__global__ void k_zero_int(int* p, int n) {
    int i = blockIdx.x * blockDim.x + threadIdx.x;
    if (i < n) p[i] = 0;
}

// ---------------- fused prep: cvtX(dense 112) | count_deg | cvtW1 | cvtW2 ----------------
#define CVX_ELEMS  (N_NODES * 28)                           // uint2 elems (4 halves each)
#define CVX_BLOCKS ((CVX_ELEMS + 255) / 256)                // 5469
#define CNT_BLOCKS  ((N_EDGES / 2 + 255) / 256)             // 977
#define CVW1_BLOCKS ((384 * K1P + 255) / 256)               // 192
#define CVW2_BLOCKS ((192 * K2P + 255) / 256)               // 264
#define PREP_BLOCKS (CVX_BLOCKS + CNT_BLOCKS + CVW1_BLOCKS + CVW2_BLOCKS)

__global__ __launch_bounds__(256) void k_prep(const float* __restrict__ x,
                                              const int* __restrict__ dst,
                                              const float* __restrict__ W1,
                                              const float* __restrict__ W2,
                                              ushort_t* __restrict__ x16,   // [N][112] unpadded
                                              int* __restrict__ dcount,
                                              ushort_t* __restrict__ w1t,   // [384][128]
                                              ushort_t* __restrict__ w2t) { // [192][352]
    int bid = blockIdx.x;
    int t = threadIdx.x;
    if (bid < CVX_BLOCKS) {                       // X fp32 -> fp16, dense (rows are 112 = 28*4)
        int i = bid * 256 + t;
        if (i < CVX_ELEMS) {
            float4 f = ((const float4*)x)[i];
            __half2 h0 = __floats2half2_rn(f.x, f.y);
            __half2 h1 = __floats2half2_rn(f.z, f.w);
            uint2 u; u.x = *(unsigned*)&h0; u.y = *(unsigned*)&h1;
            ((uint2*)x16)[i] = u;
        }
        return;
    }
    bid -= CVX_BLOCKS;
    if (bid < CNT_BLOCKS) {                       // degree count, 2 edges/thread
        int i = bid * 256 + t;
        if (i < N_EDGES / 2) {
            int2 d = ((const int2*)dst)[i];
            atomicAdd(&dcount[d.x], 1);
            atomicAdd(&dcount[d.y], 1);
        }
        return;
    }
    bid -= CNT_BLOCKS;
    if (bid < CVW1_BLOCKS) {                      // W1[K,N] -> w1t[n][k]
        int idx = bid * 256 + t;
        if (idx < 384 * K1P) {
            int n = idx / K1P, k = idx % K1P;
            float v = (n < F1 && k < F_IN) ? W1[k * F1 + n] : 0.0f;
            w1t[idx] = f16_bits(v);
        }
        return;
    }
    bid -= CVW1_BLOCKS;
    {                                             // W2[K,N] -> w2t[n][k]
        int idx = bid * 256 + t;
        if (idx < 192 * K2P) {
            int n = idx / K2P, k = idx % K2P;
            float v = (n < F2 && k < F1) ? W2[k * F2 + n] : 0.0f;
            w2t[idx] = f16_bits(v);
        }
    }
}

// ---------------- scan pass 1 (dinv fused) ----------------
__global__ __launch_bounds__(SCAN_CHUNK) void k_scan1(const int* __restrict__ dcount,
                                                      int* __restrict__ off,
                                                      int* __restrict__ partials,
                                                      float* __restrict__ dinv, int n) {
    __shared__ int s[SCAN_CHUNK];
    int t = threadIdx.x;
    int i = blockIdx.x * SCAN_CHUNK + t;
    int val = (i < n) ? dcount[i] : 0;
    s[t] = val;
    __syncthreads();
    for (int d = 1; d < SCAN_CHUNK; d <<= 1) {
        int x = (t >= d) ? s[t - d] : 0;
        __syncthreads();
        s[t] += x;
        __syncthreads();
    }
    if (i < n) {
        off[i] = s[t] - val;
        dinv[i] = rsqrtf((float)val + 1.0f);      // +1 self-loop
    }
    if (t == SCAN_CHUNK - 1) partials[blockIdx.x] = s[t];
}
// scan pass 2+3 merged
__global__ __launch_bounds__(SCAN_CHUNK) void k_scan3(int* __restrict__ off,
                                                      const int* __restrict__ partials, int n) {
    __shared__ int tmp[SCAN_BLOCKS];
    __shared__ int pref[SCAN_BLOCKS];
    int t = threadIdx.x;
    if (t < SCAN_BLOCKS) tmp[t] = partials[t];
    __syncthreads();
    if (t == 0) {
        int run = 0;
        for (int j = 0; j < SCAN_BLOCKS; ++j) { pref[j] = run; run += tmp[j]; }
    }
    __syncthreads();
    int i = blockIdx.x * SCAN_CHUNK + t;
    if (i < n) off[i] += pref[blockIdx.x];
    if (i == n) off[i] = N_EDGES;
}

// ---------------- scatter edges into dst-sorted CSR, 2 edges/thread ----------------
__global__ void k_scatter(const int* __restrict__ src, const int* __restrict__ dst,
                          const int* __restrict__ off, int* __restrict__ cur,
                          const float* __restrict__ dinv,
                          int2* __restrict__ csr, int e2) {
    int i = blockIdx.x * blockDim.x + threadIdx.x;
    if (i >= e2) return;
    int2 s2 = ((const int2*)src)[i];
    int2 d2 = ((const int2*)dst)[i];
    {
        int pos = atomicAdd(&cur[d2.x], 1);
        int2 rec; rec.x = s2.x; rec.y = __float_as_int(dinv[s2.x] * dinv[d2.x]);
        csr[off[d2.x] + pos] = rec;
    }
    {
        int pos = atomicAdd(&cur[d2.y], 1);
        int2 rec; rec.x = s2.y; rec.y = __float_as_int(dinv[s2.y] * dinv[d2.y]);
        csr[off[d2.y] + pos] = rec;
    }
}

// ---------------- agg layer 1: 2 nodes/wave, coalesced-csr + shfl, depth-8 asm gathers ----------------
__global__ __launch_bounds__(256) void k_agg1(const ushort_t* __restrict__ X16,  // [N][112]
                                              const int* __restrict__ off,
                                              const int2* __restrict__ csr,
                                              const float* __restrict__ dinv,
                                              ushort_t* __restrict__ aX) {       // [MPAD][128]
    int w = (blockIdx.x * 256 + threadIdx.x) >> 6;
    int lane = threadIdx.x & 63;
    if (w >= N_NODES / 2) return;
    const int g = lane >> 5, sl = lane & 31;
    const int slc = min(sl, 27);                  // clamp: pad lanes load row's last chunk, discard
    const int v = 2 * w + g;
    const bool act = sl < 28;                     // 28 lanes x 4 halves = 112
    int o0A = off[2 * w], oM = off[2 * w + 1], o1B = off[2 * w + 2];
    int o0 = g ? oM : o0A;
    int n  = g ? (o1B - oM) : (oM - o0A);
    int nmax = max(oM - o0A, o1B - oM);
    int total = o1B - o0A;
    float di = dinv[v];
    float s2 = di * di;
    float4 acc;
    {
        uint2 us = *(const uint2*)(X16 + (long)v * K1X + slc * 4);
        float2 sf0 = __half22float2(*(__half2*)&us.x);
        float2 sf1 = __half22float2(*(__half2*)&us.y);
        acc.x = sf0.x * s2; acc.y = sf0.y * s2; acc.z = sf1.x * s2; acc.w = sf1.y * s2;
    }
    int nm1 = max(n - 1, 0);
    if (total <= 64) {                            // fast path: whole pair's edges in one coalesced load
        int2 eall = csr[min(o0A + lane, N_EDGES - 1)];
        int ebase = o0 - o0A;
        for (int b = 0; b < nmax; b += 8) {
            int es[8]; float ec[8];
            #pragma unroll
            for (int j = 0; j < 8; ++j) {
                int widx = ebase + min(b + j, nm1);
                es[j] = __shfl(eall.x, widx);
                ec[j] = __int_as_float(__shfl(eall.y, widx));
            }
            uint2 u[8];
            #pragma unroll
            for (int j = 0; j < 8; ++j)
                gload_b64(u[j], X16 + (long)es[j] * K1X + slc * 4);
            vmwait0();
            #pragma unroll
            for (int j = 0; j < 8; ++j) {
                float c = ((b + j) < n) ? ec[j] : 0.0f;
                float2 f0 = __half22float2(*(__half2*)&u[j].x);
                float2 f1 = __half22float2(*(__half2*)&u[j].y);
                acc.x += c * f0.x; acc.y += c * f0.y; acc.z += c * f1.x; acc.w += c * f1.y;
            }
        }
    } else {                                      // rare path: per-batch broadcast csr loads (R4)
        for (int b = 0; b < nmax; b += 8) {
            int2 e[8];
            #pragma unroll
            for (int j = 0; j < 8; ++j) {
                int cidx = min(o0 + min(b + j, nm1), N_EDGES - 1);
                e[j] = csr[cidx];
            }
            uint2 u[8];
            #pragma unroll
            for (int j = 0; j < 8; ++j)
                gload_b64(u[j], X16 + (long)e[j].x * K1X + slc * 4);
            vmwait0();
            #pragma unroll
            for (int j = 0; j < 8; ++j) {
                float c = ((b + j) < n) ? __int_as_float(e[j].y) : 0.0f;
                float2 f0 = __half22float2(*(__half2*)&u[j].x);
                float2 f1 = __half22float2(*(__half2*)&u[j].y);
                acc.x += c * f0.x; acc.y += c * f0.y; acc.z += c * f1.x; acc.w += c * f1.y;
            }
        }
    }
    __half2 h0 = __floats2half2_rn(acc.x, acc.y);
    __half2 h1 = __floats2half2_rn(acc.z, acc.w);
    uint2 o; o.x = *(unsigned*)&h0; o.y = *(unsigned*)&h1;
    if (!act) { o.x = 0; o.y = 0; }               // pad lanes accumulated garbage -> zero
    *(uint2*)(aX + (long)v * K1P + sl * 4) = o;
}

// ---------------- fused GEMM1+GEMM2: T2 = (relu(aX@W1t^T + b1)) @ W2t^T ----------------
__global__ __launch_bounds__(256) void k_gemm_fused(
        const ushort_t* __restrict__ aX,    // [MPAD][128]
        const ushort_t* __restrict__ w1t,   // [384][128] rows 0..351 used
        const float* __restrict__ b1,       // [336]
        const ushort_t* __restrict__ w2t,   // [192][352]
        ushort_t* __restrict__ T2) {        // [MPAD][168]
    __shared__ ushort_t As[64][40];
    __shared__ ushort_t Bs[352][40];
    __shared__ ushort_t H1s[64][360];
    const int tid = threadIdx.x;
    const int row0 = blockIdx.x * 64;
    const int w = tid >> 6, l = tid & 63;
    const int wm = w >> 1, wn = w & 1;
    const int lm = l & 15, lq = l >> 4;

    // ---- phase 1 ----
    f32x4 acc1[2][11];
    #pragma unroll
    for (int i = 0; i < 2; ++i)
        #pragma unroll
        for (int j = 0; j < 11; ++j) acc1[i][j] = (f32x4){0.f, 0.f, 0.f, 0.f};

    for (int k0 = 0; k0 < K1P; k0 += 32) {
        {   // stage As
            int r = tid >> 2, s = (tid & 3) * 8;
            *(int4*)&As[r][s] = *(const int4*)&aX[(long)(row0 + r) * K1P + k0 + s];
        }
        #pragma unroll
        for (int it = 0; it < 6; ++it) {   // stage Bs: 352 rows x 4 segs = 1408
            int f = tid + it * 256;
            if (f < 1408) {
                int r = f >> 2, s = (f & 3) * 8;
                *(int4*)&Bs[r][s] = *(const int4*)&w1t[(long)r * K1P + k0 + s];
            }
        }
        __syncthreads();
        f16x8 af0 = *(const f16x8*)&As[wm * 32 + lm][lq * 8];
        f16x8 af1 = *(const f16x8*)&As[wm * 32 + 16 + lm][lq * 8];
        #pragma unroll
        for (int ns = 0; ns < 11; ++ns) {
            f16x8 bf = *(const f16x8*)&Bs[wn * 176 + ns * 16 + lm][lq * 8];
            acc1[0][ns] = __builtin_amdgcn_mfma_f32_16x16x32_f16(af0, bf, acc1[0][ns], 0, 0, 0);
            acc1[1][ns] = __builtin_amdgcn_mfma_f32_16x16x32_f16(af1, bf, acc1[1][ns], 0, 0, 0);
        }
        __syncthreads();
    }
    // write H1 tile to LDS with bias+relu (C/D layout: col=lm, row=lq*4+i)
    #pragma unroll
    for (int ms = 0; ms < 2; ++ms)
        #pragma unroll
        for (int ns = 0; ns < 11; ++ns) {
            int col = wn * 176 + ns * 16 + lm;
            float bb = (col < F1) ? b1[col] : 0.0f;
            #pragma unroll
            for (int i = 0; i < 4; ++i) {
                int r = wm * 32 + ms * 16 + lq * 4 + i;
                H1s[r][col] = f16_bits(fmaxf(acc1[ms][ns][i] + bb, 0.0f));
            }
        }
    __syncthreads();

    // ---- phase 2 ----
    f32x4 acc2[2][6];
    #pragma unroll
    for (int i = 0; i < 2; ++i)
        #pragma unroll
        for (int j = 0; j < 6; ++j) acc2[i][j] = (f32x4){0.f, 0.f, 0.f, 0.f};

    for (int k0 = 0; k0 < K2P; k0 += 32) {
        #pragma unroll
        for (int it = 0; it < 3; ++it) {   // stage Bs2: 192 rows x 4 segs = 768
            int f = tid + it * 256;
            int r = f >> 2, s = (f & 3) * 8;
            *(int4*)&Bs[r][s] = *(const int4*)&w2t[(long)r * K2P + k0 + s];
        }
        __syncthreads();
        f16x8 af0 = *(const f16x8*)&H1s[wm * 32 + lm][k0 + lq * 8];
        f16x8 af1 = *(const f16x8*)&H1s[wm * 32 + 16 + lm][k0 + lq * 8];
        #pragma unroll
        for (int ns = 0; ns < 6; ++ns) {
            f16x8 bf = *(const f16x8*)&Bs[wn * 96 + ns * 16 + lm][lq * 8];
            acc2[0][ns] = __builtin_amdgcn_mfma_f32_16x16x32_f16(af0, bf, acc2[0][ns], 0, 0, 0);
            acc2[1][ns] = __builtin_amdgcn_mfma_f32_16x16x32_f16(af1, bf, acc2[1][ns], 0, 0, 0);
        }
        __syncthreads();
    }
    #pragma unroll
    for (int ms = 0; ms < 2; ++ms)
        #pragma unroll
        for (int ns = 0; ns < 6; ++ns) {
            int col = wn * 96 + ns * 16 + lm;
            if (col < F2) {
                #pragma unroll
                for (int i = 0; i < 4; ++i) {
                    int r = row0 + wm * 32 + ms * 16 + lq * 4 + i;
                    T2[(long)r * F2 + col] = f16_bits(acc2[ms][ns][i]);
                }
            }
        }
}

// ---------------- agg layer 2 + fused global-max-pool (coalesced-csr + shfl, depth-8) ----------------
// 2 nodes/wave, bias+relu in f32, per-block segment max -> atomicMax(int) on gmax.
// Valid because post-relu values are >= 0 (int-bit compare == float compare) and gmax init = 0.
__global__ __launch_bounds__(256) void k_agg2(const ushort_t* __restrict__ T16,   // [MPAD][168]
                                              const int* __restrict__ off,
                                              const int2* __restrict__ csr,
                                              const float* __restrict__ dinv,
                                              const float* __restrict__ b2,
                                              const int* __restrict__ batch,
                                              float* __restrict__ gmax) {         // [256][168]
    __shared__ __align__(16) float smax[8][168];
    __shared__ int sb[8];
    int tid = threadIdx.x;
    // grid is exactly N_NODES/8 blocks -> every thread has a valid node (no early return: barrier below)
    int w = (blockIdx.x * 256 + tid) >> 6;
    int lane = tid & 63;
    const int g = lane >> 5, sl = lane & 31;
    const int slc = min(sl, 20);                  // clamp: pad lanes load row tail, discard
    const int nib = tid >> 5;                     // node-in-block 0..7
    const int v = 2 * w + g;                      // == blockIdx.x*8 + nib
    const bool act = sl < 21;                     // 21 lanes x 8 halves = 168
    int o0A = off[2 * w], oM = off[2 * w + 1], o1B = off[2 * w + 2];
    int o0 = g ? oM : o0A;
    int n  = g ? (o1B - oM) : (oM - o0A);
    int nmax = max(oM - o0A, o1B - oM);
    int total = o1B - o0A;
    float di = dinv[v];
    float4 a0, a1;
    {
        uint4 u = *(const uint4*)(T16 + (long)v * F2 + slc * 8);
        float2 f0 = __half22float2(*(__half2*)&u.x);
        float2 f1 = __half22float2(*(__half2*)&u.y);
        float2 f2 = __half22float2(*(__half2*)&u.z);
        float2 f3 = __half22float2(*(__half2*)&u.w);
        float s2 = di * di;
        a0.x = f0.x * s2; a0.y = f0.y * s2; a0.z = f1.x * s2; a0.w = f1.y * s2;
        a1.x = f2.x * s2; a1.y = f2.y * s2; a1.z = f3.x * s2; a1.w = f3.y * s2;
    }
    int nm1 = max(n - 1, 0);
    if (total <= 64) {                            // fast path: one coalesced csr load per pair
        int2 eall = csr[min(o0A + lane, N_EDGES - 1)];
        int ebase = o0 - o0A;
        for (int b = 0; b < nmax; b += 8) {
            int es[8]; float ec[8];
            #pragma unroll
            for (int j = 0; j < 8; ++j) {
                int widx = ebase + min(b + j, nm1);
                es[j] = __shfl(eall.x, widx);
                ec[j] = __int_as_float(__shfl(eall.y, widx));
            }
            uint4 u[8];
            #pragma unroll
            for (int j = 0; j < 8; ++j)
                gload_b128(u[j], T16 + (long)es[j] * F2 + slc * 8);
            vmwait0();
            #pragma unroll
            for (int j = 0; j < 8; ++j) {
                float c = ((b + j) < n) ? ec[j] : 0.0f;
                float2 f0 = __half22float2(*(__half2*)&u[j].x);
                float2 f1 = __half22float2(*(__half2*)&u[j].y);
                float2 f2 = __half22float2(*(__half2*)&u[j].z);
                float2 f3 = __half22float2(*(__half2*)&u[j].w);
                a0.x += c * f0.x; a0.y += c * f0.y; a0.z += c * f1.x; a0.w += c * f1.y;
                a1.x += c * f2.x; a1.y += c * f2.y; a1.z += c * f3.x; a1.w += c * f3.y;
            }
        }
    } else {                                      // rare path: per-batch broadcast csr loads (R4)
        for (int b = 0; b < nmax; b += 8) {
            int2 e[8];
            #pragma unroll
            for (int j = 0; j < 8; ++j) {
                int cidx = min(o0 + min(b + j, nm1), N_EDGES - 1);
                e[j] = csr[cidx];
            }
            uint4 u[8];
            #pragma unroll
            for (int j = 0; j < 8; ++j)
                gload_b128(u[j], T16 + (long)e[j].x * F2 + slc * 8);
            vmwait0();
            #pragma unroll
            for (int j = 0; j < 8; ++j) {
                float c = ((b + j) < n) ? __int_as_float(e[j].y) : 0.0f;
                float2 f0 = __half22float2(*(__half2*)&u[j].x);
                float2 f1 = __half22float2(*(__half2*)&u[j].y);
                float2 f2 = __half22float2(*(__half2*)&u[j].z);
                float2 f3 = __half22float2(*(__half2*)&u[j].w);
                a0.x += c * f0.x; a0.y += c * f0.y; a0.z += c * f1.x; a0.w += c * f1.y;
                a1.x += c * f2.x; a1.y += c * f2.y; a1.z += c * f3.x; a1.w += c * f3.y;
            }
        }
    }
    if (act) {
        float4 bb0 = ((const float4*)b2)[sl * 2];
        float4 bb1 = ((const float4*)b2)[sl * 2 + 1];
        a0.x = fmaxf(a0.x + bb0.x, 0.0f); a0.y = fmaxf(a0.y + bb0.y, 0.0f);
        a0.z = fmaxf(a0.z + bb0.z, 0.0f); a0.w = fmaxf(a0.w + bb0.w, 0.0f);
        a1.x = fmaxf(a1.x + bb1.x, 0.0f); a1.y = fmaxf(a1.y + bb1.y, 0.0f);
        a1.z = fmaxf(a1.z + bb1.z, 0.0f); a1.w = fmaxf(a1.w + bb1.w, 0.0f);
        ((float4*)&smax[nib][0])[sl * 2]     = a0;
        ((float4*)&smax[nib][0])[sl * 2 + 1] = a1;
    }
    if ((tid & 31) == 0) sb[nib] = batch[v];
    __syncthreads();
    if (tid < F2) {
        int f = tid;
        int bp = sb[0];
        float m = smax[0][f];
        #pragma unroll
        for (int r = 1; r < 8; ++r) {
            int bc = sb[r];
            float vv = smax[r][f];
            if (bc == bp) { m = fmaxf(m, vv); }
            else {
                atomicMax((int*)&gmax[bp * F2 + f], __float_as_int(m));
                m = vv; bp = bc;
            }
        }
        atomicMax((int*)&gmax[bp * F2 + f], __float_as_int(m));
    }
}

// ---------------- MLP head on pooled [256][168] ----------------
__global__ __launch_bounds__(128) void k_head(const float* __restrict__ gmax,
        const float* __restrict__ Wg, const float* __restrict__ bg,
        const float* __restrict__ Wf, const float* __restrict__ bf,
        const float* __restrict__ Wo, const float* __restrict__ bo,
        float* __restrict__ out) {
    __shared__ float s1[84];
    __shared__ float s2[42];
    int gi = blockIdx.x;
    const float* s0 = gmax + (long)gi * F2;
    int t = threadIdx.x;
    if (t < 84) {
        float acc = bg[t];
        #pragma unroll 4
        for (int k = 0; k < F2; ++k) acc += s0[k] * Wg[k * 84 + t];
        s1[t] = fmaxf(acc, 0.0f);
    }
    __syncthreads();
    if (t < 42) {
        float acc = bf[t];
        #pragma unroll 4
        for (int k = 0; k < 84; ++k) acc += s1[k] * Wf[k * 42 + t];
        s2[t] = fmaxf(acc, 0.0f);
    }
    __syncthreads();
    if (t == 0) {
        float acc = bo[0];
        for (int k = 0; k < 42; ++k) acc += s2[k] * Wo[k];
        out[gi] = acc;
    }
}

extern "C" void kernel_launch(void* const* d_in, const int* in_sizes, int n_in,
                              void* d_out, int out_size, void* d_ws, size_t ws_size,
                              hipStream_t stream) {
    const float* x   = (const float*)d_in[0];
    const int*   ei  = (const int*)d_in[1];
    const int*   bat = (const int*)d_in[2];
    const float* W1  = (const float*)d_in[3];
    const float* b1  = (const float*)d_in[4];
    const float* W2  = (const float*)d_in[5];
    const float* b2  = (const float*)d_in[6];
    const float* Wg  = (const float*)d_in[7];
    const float* bg  = (const float*)d_in[8];
    const float* Wf  = (const float*)d_in[9];
    const float* bf  = (const float*)d_in[10];
    const float* Wo  = (const float*)d_in[11];
    const float* bo  = (const float*)d_in[12];
    float* out = (float*)d_out;

    // ---- workspace carve-up (16B-aligned chunks; dcount+cur+gmax adjacent for one zero-fill) ----
    char* p = (char*)d_ws;
    float* dinv     = (float*)p; p += 50048 * 4;
    int*   dcount   = (int*)p;   p += 50048 * 4;
    int*   cur      = (int*)p;   p += 50048 * 4;
    float* gmax     = (float*)p; p += NGRAPH * F2 * 4;              // 43008 floats
    int*   off      = (int*)p;   p += 50064 * 4;
    int*   partials = (int*)p;   p += 64 * 4;
    int2*  csr      = (int2*)p;  p += (long)N_EDGES * 8;
    ushort_t* x16   = (ushort_t*)p; p += (long)N_NODES * K1X * 2;   // unpadded 112
    ushort_t* aX    = (ushort_t*)p; p += (long)MPAD * K1P * 2;      // padded 128
    ushort_t* w1t   = (ushort_t*)p; p += (long)384 * K1P * 2;
    ushort_t* w2t   = (ushort_t*)p; p += (long)192 * K2P * 2;
    ushort_t* t16   = (ushort_t*)p; p += (long)MPAD * F2 * 2;       // unpadded 168

    const int* src = ei;
    const int* dst = ei + N_EDGES;
    const int B = 256;
    const int ZERO_WORDS = 50048 * 2 + NGRAPH * F2;                 // dcount+cur+gmax

    // ---- preproc ----
    k_zero_int<<<(ZERO_WORDS + B - 1) / B, B, 0, stream>>>(dcount, ZERO_WORDS);
    k_prep<<<PREP_BLOCKS, B, 0, stream>>>(x, dst, W1, W2, x16, dcount, w1t, w2t);
    k_scan1<<<SCAN_BLOCKS, SCAN_CHUNK, 0, stream>>>(dcount, off, partials, dinv, N_NODES);
    k_scan3<<<SCAN_BLOCKS, SCAN_CHUNK, 0, stream>>>(off, partials, N_NODES);
    k_scatter<<<(N_EDGES / 2 + B - 1) / B, B, 0, stream>>>(src, dst, off, cur, dinv, csr, N_EDGES / 2);

    // ---- layer 1 agg + fused GEMM1/GEMM2 ----
    k_agg1<<<(N_NODES / 2 * 64) / 256, 256, 0, stream>>>(x16, off, csr, dinv, aX);
    k_gemm_fused<<<MPAD / 64, 256, 0, stream>>>(aX, w1t, b1, w2t, t16);

    // ---- layer 2 agg + fused max-pool ----
    k_agg2<<<(N_NODES / 2 * 64) / 256, 256, 0, stream>>>(t16, off, csr, dinv, b2, bat, gmax);

    // ---- MLP head ----
    k_head<<<NGRAPH, 128, 0, stream>>>(gmax, Wg, bg, Wf, bf, Wo, bo, out);
}